// Round 12
// baseline (302.975 us; speedup 1.0000x reference)
//
#include <hip/hip_runtime.h>

#define T_TOK 16
#define K_TOP 8
#define NEXP  64
#define DHID  2048
#define FINT  1024

typedef unsigned int   uint_t;
typedef unsigned short ushort_t;
typedef float f32x4 __attribute__((ext_vector_type(4)));
typedef float f32x2 __attribute__((ext_vector_type(2)));

// workspace layout (bytes)
#define ROUTE_OFF 0u          // 64*16 fp32 = 4 KB
#define AIDX_OFF  4096u       // 64 int
#define NA_OFF    4352u       // 1 int
#define WCTRU_OFF 4356u       // 1 int
#define WCTRD_OFF 4360u       // 1 int
#define XTBF_OFF  8192u       // 2048*16 bf16 = 64 KB
#define ABUF_OFF  131072u     // 64*1024*16 bf16 = 2 MB
#define OPART_OFF 2228224u    // 64*16*2048 bf16 = 4 MB
#define PART8_OFF 6422528u    // 8*16*2048 fp32 = 1 MB

__device__ __forceinline__ ushort_t f2bf(float f) {
    uint_t u = __builtin_bit_cast(uint_t, f);
    u += 0x7FFFu + ((u >> 16) & 1u);   // RNE
    return (ushort_t)(u >> 16);
}
__device__ __forceinline__ uint_t pk2(float lo, float hi) {
    return (uint_t)f2bf(lo) | ((uint_t)f2bf(hi) << 16);
}
__device__ __forceinline__ float bf_lo(uint_t v) { return __builtin_bit_cast(float, v << 16); }
__device__ __forceinline__ float bf_hi(uint_t v) { return __builtin_bit_cast(float, v & 0xFFFF0000u); }

// ---------------------------------------------------------------------------
// K1: xt_bf [d][t] bf16-packed (32 blocks) + route/aidx/nA + counter resets.
// ---------------------------------------------------------------------------
__global__ void k_prep(const float* __restrict__ x, const int* __restrict__ idx,
                       const float* __restrict__ w, uint_t* __restrict__ xt_bf,
                       float* __restrict__ route, int* __restrict__ aidx,
                       int* __restrict__ nA, int* __restrict__ wctru,
                       int* __restrict__ wctrd) {
    const int tid = threadIdx.x;                 // 256
    const int d = blockIdx.x * 64 + (tid & 63);
    const int tq = tid >> 6;
    float4 v;
    v.x = x[(tq * 4 + 0) * DHID + d];
    v.y = x[(tq * 4 + 1) * DHID + d];
    v.z = x[(tq * 4 + 2) * DHID + d];
    v.w = x[(tq * 4 + 3) * DHID + d];
    *reinterpret_cast<uint2*>(xt_bf + d * 8 + tq * 2) =
        make_uint2(pk2(v.x, v.y), pk2(v.z, v.w));

    if (blockIdx.x != 0) return;
    if (tid == 0) { *wctru = 0; *wctrd = 0; }
    __shared__ float r[NEXP * T_TOK];
    __shared__ int is64_s;
    if (tid == 0) {
        int allz = 1;
        for (int i = 1; i < 128; i += 2) allz &= (idx[i] == 0);
        is64_s = allz;
    }
    __syncthreads();
    const int is64 = is64_s;
    for (int i = tid; i < NEXP * T_TOK; i += 256) {
        const int e = i >> 4, t = i & 15;
        float s = 0.f;
#pragma unroll
        for (int k = 0; k < K_TOP; ++k) {
            const int flat = t * K_TOP + k;
            const int ev = is64 ? idx[2 * flat] : idx[flat];
            if (ev == e) s += w[flat];
        }
        r[i] = s;
        route[i] = s;
    }
    __syncthreads();
    if (tid == 0) {
        int n = 0;
        for (int e = 0; e < NEXP; ++e) {
            float s = 0.f;
            for (int t = 0; t < T_TOK; ++t) s += r[e * T_TOK + t];
            if (s != 0.f) aidx[n++] = e;
        }
        *nA = n;
    }
}

// ---- inner-loop machinery --------------------------------------------------
#define FMA4(t, xs)                              \
    acc0[t] = fmaf((xs), w4.x, acc0[t]);         \
    acc1[t] = fmaf((xs), w4.y, acc1[t]);         \
    acc2[t] = fmaf((xs), w4.z, acc2[t]);         \
    acc3[t] = fmaf((xs), w4.w, acc3[t]);
#define FMA_PAIR(u, t0_)                                        \
    { const float xl = bf_lo(u), xh = bf_hi(u);                 \
      FMA4(t0_, xl) FMA4((t0_) + 1, xh) }
#define STEP(jj, B)                                                         \
    { const uint4 q0 = xqw[(jj) * 2]; const uint4 q1 = xqw[(jj) * 2 + 1];   \
      const f32x4 w4 = (B);                                                 \
      FMA_PAIR(q0.x, 0) FMA_PAIR(q0.y, 2) FMA_PAIR(q0.z, 4) FMA_PAIR(q0.w, 6) \
      FMA_PAIR(q1.x, 8) FMA_PAIR(q1.y, 10) FMA_PAIR(q1.z, 12) FMA_PAIR(q1.w, 14) }
#define LDW(j) __builtin_nontemporal_load(wrow + (size_t)(j) * WSTEP)
#define STREAM64()                                                 \
    { f32x4 b0 = LDW(0), b1 = LDW(1), b2 = LDW(2), b3 = LDW(3);    \
      for (int j = 0; j < 64; j += 4) {                            \
          const bool pf = (j < 60);                                \
          STEP(j + 0, b0) if (pf) b0 = LDW(j + 4);                 \
          STEP(j + 1, b1) if (pf) b1 = LDW(j + 5);                 \
          STEP(j + 2, b2) if (pf) b2 = LDW(j + 6);                 \
          STEP(j + 3, b3) if (pf) b3 = LDW(j + 7); } }

// 2-col variants (up kernel, f32x2 weights)
#define FMA_P2(u, t0_)                                                    \
    { const float xl = bf_lo(u), xh = bf_hi(u);                           \
      acc0[t0_] = fmaf(xl, w2.x, acc0[t0_]);                              \
      acc1[t0_] = fmaf(xl, w2.y, acc1[t0_]);                              \
      acc0[(t0_) + 1] = fmaf(xh, w2.x, acc0[(t0_) + 1]);                  \
      acc1[(t0_) + 1] = fmaf(xh, w2.y, acc1[(t0_) + 1]); }
#define STEP2(jj, B)                                                        \
    { const uint4 q0 = xqw[(jj) * 2]; const uint4 q1 = xqw[(jj) * 2 + 1];   \
      const f32x2 w2 = (B);                                                 \
      FMA_P2(q0.x, 0) FMA_P2(q0.y, 2) FMA_P2(q0.z, 4) FMA_P2(q0.w, 6)       \
      FMA_P2(q1.x, 8) FMA_P2(q1.y, 10) FMA_P2(q1.z, 12) FMA_P2(q1.w, 14) }
#define STREAM128_2()                                                \
    { f32x2 b0 = LDW(0), b1 = LDW(1), b2 = LDW(2), b3 = LDW(3);      \
      for (int j = 0; j < 128; j += 4) {                             \
          const bool pf = (j < 124);                                 \
          STEP2(j + 0, b0) if (pf) b0 = LDW(j + 4);                  \
          STEP2(j + 1, b1) if (pf) b1 = LDW(j + 5);                  \
          STEP2(j + 2, b2) if (pf) b2 = LDW(j + 6);                  \
          STEP2(j + 3, b3) if (pf) b3 = LDW(j + 7); } }

// 4-acc bf16 region = 2048 uints (8 KB): [j(4)][tp(8)][lane(64)]
#define RW(reg)                                                          \
    { uint_t* p = tree + (reg) * 2048 + lane;                            \
      _Pragma("unroll") for (int tp = 0; tp < 8; ++tp) {                 \
          p[(0 * 8 + tp) * 64] = pk2(acc0[2 * tp], acc0[2 * tp + 1]);    \
          p[(1 * 8 + tp) * 64] = pk2(acc1[2 * tp], acc1[2 * tp + 1]);    \
          p[(2 * 8 + tp) * 64] = pk2(acc2[2 * tp], acc2[2 * tp + 1]);    \
          p[(3 * 8 + tp) * 64] = pk2(acc3[2 * tp], acc3[2 * tp + 1]); } }
#define RR(reg)                                                          \
    { const uint_t* p = tree + (reg) * 2048 + lane;                      \
      _Pragma("unroll") for (int tp = 0; tp < 8; ++tp) {                 \
          uint_t u;                                                      \
          u = p[(0 * 8 + tp) * 64]; acc0[2 * tp] += bf_lo(u); acc0[2 * tp + 1] += bf_hi(u); \
          u = p[(1 * 8 + tp) * 64]; acc1[2 * tp] += bf_lo(u); acc1[2 * tp + 1] += bf_hi(u); \
          u = p[(2 * 8 + tp) * 64]; acc2[2 * tp] += bf_lo(u); acc2[2 * tp + 1] += bf_hi(u); \
          u = p[(3 * 8 + tp) * 64]; acc3[2 * tp] += bf_lo(u); acc3[2 * tp + 1] += bf_hi(u); } }

// 2-acc bf16 region = 1024 uints (4 KB): [j(2)][tp(8)][lane(64)]
#define RW2(reg)                                                         \
    { uint_t* p = tree + (reg) * 1024 + lane;                            \
      _Pragma("unroll") for (int tp = 0; tp < 8; ++tp) {                 \
          p[(0 * 8 + tp) * 64] = pk2(acc0[2 * tp], acc0[2 * tp + 1]);    \
          p[(1 * 8 + tp) * 64] = pk2(acc1[2 * tp], acc1[2 * tp + 1]); } }
#define RR2(reg)                                                         \
    { const uint_t* p = tree + (reg) * 1024 + lane;                      \
      _Pragma("unroll") for (int tp = 0; tp < 8; ++tp) {                 \
          uint_t u;                                                      \
          u = p[(0 * 8 + tp) * 64]; acc0[2 * tp] += bf_lo(u); acc0[2 * tp + 1] += bf_hi(u); \
          u = p[(1 * 8 + tp) * 64]; acc1[2 * tp] += bf_lo(u); acc1[2 * tp + 1] += bf_hi(u); } }

// 16-wave -> wave0 tree (8 regions of the given macro pair)
#define TREE16(RWm, RRm)                           \
    __syncthreads();                               \
    if (wid >= 8) RWm(wid - 8)                     \
    __syncthreads();                               \
    if (wid < 8) RRm(wid)                          \
    __syncthreads();                               \
    if (wid >= 4 && wid < 8) RWm(wid - 4)          \
    __syncthreads();                               \
    if (wid < 4) RRm(wid)                          \
    __syncthreads();                               \
    if (wid >= 2 && wid < 4) RWm(wid - 2)          \
    __syncthreads();                               \
    if (wid < 2) RRm(wid)                          \
    __syncthreads();                               \
    if (wid == 1) RWm(0)                           \
    __syncthreads();

// ---------------------------------------------------------------------------
// K2: up-proj, persistent dynamic. 256 blocks x 1024 thr. Unit = (e, f8):
// 128-f slice, 1 MB of Wu. Wave owns 128 d-rows, lane owns 2 f (f32x2).
// TREE16 over d -> wave0 applies relu^2*route, writes a_buf slice (bf16).
// Counter is RELAXED atomic only (no fences) -> no cache maintenance.
// ---------------------------------------------------------------------------
__global__ __launch_bounds__(1024, 4) void k_up_p(
    const uint_t* __restrict__ xt_bf, const float* __restrict__ Wu,
    const float* __restrict__ route, const int* __restrict__ aidx,
    const int* __restrict__ nAp, int* wctr, ushort_t* __restrict__ a_buf) {
    const int tid = threadIdx.x;
    const int wid = tid >> 6, lane = tid & 63;

    __shared__ __align__(16) uint_t lds_u[16384 + 8192];  // 64 KB x + 32 KB tree
    uint_t* tree = lds_u + 16384;
    __shared__ int s_item;

    {   // stage full x bf16: 4096 uint4
        const uint4* src = reinterpret_cast<const uint4*>(xt_bf);
        uint4* dst = reinterpret_cast<uint4*>(lds_u);
        dst[tid] = src[tid];
        dst[tid + 1024] = src[tid + 1024];
        dst[tid + 2048] = src[tid + 2048];
        dst[tid + 3072] = src[tid + 3072];
    }
    const int nU = 8 * (*nAp);
    __syncthreads();

    for (;;) {
        if (tid == 0)
            s_item = __hip_atomic_fetch_add(wctr, 1, __ATOMIC_RELAXED, __HIP_MEMORY_SCOPE_AGENT);
        __syncthreads();
        const int item = s_item;
        if (item >= nU) break;
        const int e = aidx[item >> 3];
        const int f8 = item & 7;

        float acc0[16] = {}, acc1[16] = {};
        const f32x2* wrow = reinterpret_cast<const f32x2*>(
            Wu + (size_t)e * ((size_t)DHID * FINT)
               + (size_t)(wid * 128) * FINT + f8 * 128 + lane * 2);
        const size_t WSTEP = FINT / 2;
        const uint4* xqw = reinterpret_cast<const uint4*>(lds_u) + (size_t)wid * 256;
        STREAM128_2()
        TREE16(RW2, RR2)
        if (wid == 0) {
            RR2(0)
            float rt[16];
#pragma unroll
            for (int t = 0; t < 16; ++t) rt[t] = route[e * T_TOK + t];
#define ACT(A, t) (rt[t] * fmaxf(A[t], 0.f) * fmaxf(A[t], 0.f))
            uint4* ap = reinterpret_cast<uint4*>(
                a_buf + ((size_t)e * FINT + f8 * 128 + lane * 2) * T_TOK);
            uint4 o;
            o.x = pk2(ACT(acc0, 0), ACT(acc0, 1));   o.y = pk2(ACT(acc0, 2), ACT(acc0, 3));
            o.z = pk2(ACT(acc0, 4), ACT(acc0, 5));   o.w = pk2(ACT(acc0, 6), ACT(acc0, 7));
            ap[0] = o;
            o.x = pk2(ACT(acc0, 8), ACT(acc0, 9));   o.y = pk2(ACT(acc0, 10), ACT(acc0, 11));
            o.z = pk2(ACT(acc0, 12), ACT(acc0, 13)); o.w = pk2(ACT(acc0, 14), ACT(acc0, 15));
            ap[1] = o;
            o.x = pk2(ACT(acc1, 0), ACT(acc1, 1));   o.y = pk2(ACT(acc1, 2), ACT(acc1, 3));
            o.z = pk2(ACT(acc1, 4), ACT(acc1, 5));   o.w = pk2(ACT(acc1, 6), ACT(acc1, 7));
            ap[2] = o;
            o.x = pk2(ACT(acc1, 8), ACT(acc1, 9));   o.y = pk2(ACT(acc1, 10), ACT(acc1, 11));
            o.z = pk2(ACT(acc1, 12), ACT(acc1, 13)); o.w = pk2(ACT(acc1, 14), ACT(acc1, 15));
            ap[3] = o;
#undef ACT
        }
        __syncthreads();
    }
}

// ---------------------------------------------------------------------------
// K3: down-proj, persistent dynamic. 256 blocks x 1024 thr. Unit = (e, d8):
// 256-d slice, 1 MB of Wd. Wave owns 64 f-rows, lane owns 4 d (f32x4).
// Stages a[e] (32 KB bf16) per unit. TREE16 over f -> wave0 writes bf16
// out_part[e][t][d-slice] (single writer per unit).
// ---------------------------------------------------------------------------
__global__ __launch_bounds__(1024, 4) void k_down_p(
    const ushort_t* __restrict__ a_buf, const float* __restrict__ Wd,
    const int* __restrict__ aidx, const int* __restrict__ nAp,
    int* wctr, ushort_t* __restrict__ out_part) {
    const int tid = threadIdx.x;
    const int wid = tid >> 6, lane = tid & 63;

    __shared__ __align__(16) uint_t lds_u[8192 + 16384];  // 32 KB a + 64 KB tree
    uint_t* tree = lds_u + 8192;
    __shared__ int s_item;

    const int nU = 8 * (*nAp);

    for (;;) {
        if (tid == 0)
            s_item = __hip_atomic_fetch_add(wctr, 1, __ATOMIC_RELAXED, __HIP_MEMORY_SCOPE_AGENT);
        __syncthreads();
        const int item = s_item;
        if (item >= nU) break;
        const int e = aidx[item >> 3];
        const int d8 = item & 7;

        {   // stage a[e] bf16: 32 KB = 2048 uint4 (two stores per thread)
            const uint4* src = reinterpret_cast<const uint4*>(
                a_buf + (size_t)e * FINT * T_TOK);
            uint4* dst = reinterpret_cast<uint4*>(lds_u);
            dst[tid] = src[tid];
            dst[tid + 1024] = src[tid + 1024];
        }
        __syncthreads();

        float acc0[16] = {}, acc1[16] = {}, acc2[16] = {}, acc3[16] = {};
        const f32x4* wrow = reinterpret_cast<const f32x4*>(
            Wd + (size_t)e * ((size_t)FINT * DHID)
               + (size_t)(wid * 64) * DHID + d8 * 256 + lane * 4);
        const size_t WSTEP = DHID / 4;
        const uint4* xqw = reinterpret_cast<const uint4*>(lds_u) + (size_t)wid * 128;
        STREAM64()
        TREE16(RW, RR)
        if (wid == 0) {
            RR(0)
            ushort_t* op = out_part + (size_t)e * (T_TOK * DHID) + d8 * 256 + lane * 4;
#pragma unroll
            for (int t = 0; t < 16; ++t) {
                uint2 u;
                u.x = pk2(acc0[t], acc1[t]);
                u.y = pk2(acc2[t], acc3[t]);
                *reinterpret_cast<uint2*>(op + (size_t)t * DHID) = u;
            }
        }
        __syncthreads();
    }
}

// ---------------------------------------------------------------------------
// K4a: partial[g][t][d] = sum over active experts a = g, g+8, ... (fp32).
// grid (32, 8) x 256 -> 256 blocks; fully overwrites partial.
// ---------------------------------------------------------------------------
__global__ void k_comb1(const ushort_t* __restrict__ out_part, const int* __restrict__ aidx,
                        const int* __restrict__ nAp, float* __restrict__ partial) {
    const int g = blockIdx.y;
    const int i = blockIdx.x * 256 + threadIdx.x;  // [0, T*D/4)
    const int nA = *nAp;
    const int t = i >> 9;
    const int d = (i & 511) * 4;
    const size_t off = (size_t)t * DHID + d;
    float s0 = 0.f, s1 = 0.f, s2 = 0.f, s3 = 0.f;
    for (int a = g; a < nA; a += 8) {
        const uint2 v = *reinterpret_cast<const uint2*>(
            out_part + (size_t)aidx[a] * (T_TOK * DHID) + off);
        s0 += bf_lo(v.x); s1 += bf_hi(v.x);
        s2 += bf_lo(v.y); s3 += bf_hi(v.y);
    }
    *reinterpret_cast<float4*>(partial + (size_t)g * (T_TOK * DHID) + off) =
        make_float4(s0, s1, s2, s3);
}

// ---------------------------------------------------------------------------
// K4b: out[t][d] = sum_g partial[g][t][d]. Fully overwrites d_out.
// ---------------------------------------------------------------------------
__global__ void k_comb2(const float* __restrict__ partial, float* __restrict__ out) {
    const int i = blockIdx.x * 256 + threadIdx.x;  // [0, T*D/4)
    const size_t off = (size_t)i * 4;
    float4 s = make_float4(0.f, 0.f, 0.f, 0.f);
#pragma unroll
    for (int g = 0; g < 8; ++g) {
        const float4 v = *reinterpret_cast<const float4*>(
            partial + (size_t)g * (T_TOK * DHID) + off);
        s.x += v.x; s.y += v.y; s.z += v.z; s.w += v.w;
    }
    *reinterpret_cast<float4*>(out + off) = s;
}

// ---------------------------------------------------------------------------
extern "C" void kernel_launch(void* const* d_in, const int* in_sizes, int n_in,
                              void* d_out, int out_size, void* d_ws, size_t ws_size,
                              hipStream_t stream) {
    (void)in_sizes; (void)n_in; (void)out_size; (void)ws_size;
    const float* x   = (const float*)d_in[0];
    const int*   idx = (const int*)d_in[1];
    const float* w   = (const float*)d_in[2];
    const float* Wu  = (const float*)d_in[3];
    const float* Wd  = (const float*)d_in[4];
    float* out = (float*)d_out;

    char* ws = (char*)d_ws;
    float*    route    = (float*)(ws + ROUTE_OFF);
    int*      aidx     = (int*)(ws + AIDX_OFF);
    int*      nA       = (int*)(ws + NA_OFF);
    int*      wctru    = (int*)(ws + WCTRU_OFF);
    int*      wctrd    = (int*)(ws + WCTRD_OFF);
    uint_t*   xt_bf    = (uint_t*)(ws + XTBF_OFF);
    ushort_t* a_buf    = (ushort_t*)(ws + ABUF_OFF);
    ushort_t* out_part = (ushort_t*)(ws + OPART_OFF);
    float*    partial  = (float*)(ws + PART8_OFF);

    k_prep<<<DHID / 64, 256, 0, stream>>>(x, idx, w, xt_bf, route, aidx, nA, wctru, wctrd);
    k_up_p<<<256, 1024, 0, stream>>>(xt_bf, Wu, route, aidx, nA, wctru, a_buf);
    k_down_p<<<256, 1024, 0, stream>>>(a_buf, Wd, aidx, nA, wctrd, out_part);
    k_comb1<<<dim3(32, 8), 256, 0, stream>>>(out_part, aidx, nA, partial);
    k_comb2<<<32, 256, 0, stream>>>(partial, out);
}

// Round 13
// 184.658 us; speedup vs baseline: 1.6407x; 1.6407x over previous
//
#include <hip/hip_runtime.h>

#define T_TOK 16
#define K_TOP 8
#define NEXP  64
#define DHID  2048
#define FINT  1024

typedef unsigned int   uint_t;
typedef unsigned short ushort_t;
typedef float f32x4 __attribute__((ext_vector_type(4)));

// workspace layout (bytes)
#define ROUTE_OFF 0u
#define AIDX_OFF  4096u
#define NA_OFF    (AIDX_OFF + 256u)
#define XT_OFF    8192u                          // 2048*16 fp32 = 128 KB
#define ABUF_OFF  (XT_OFF + 131072u)             // 64*1024*16 bf16 = 2 MB
#define OPART_OFF (ABUF_OFF + 2097152u)          // 64*16*2048 bf16 = 4 MB
#define PART8_OFF (OPART_OFF + 4194304u)         // 8*16*2048 fp32 = 1 MB

__device__ __forceinline__ ushort_t f2bf(float f) {
    uint_t u = __builtin_bit_cast(uint_t, f);
    u += 0x7FFFu + ((u >> 16) & 1u);   // RNE
    return (ushort_t)(u >> 16);
}
__device__ __forceinline__ uint_t pk2(float lo, float hi) {
    return (uint_t)f2bf(lo) | ((uint_t)f2bf(hi) << 16);
}
__device__ __forceinline__ float bf_lo(uint_t v) { return __builtin_bit_cast(float, v << 16); }
__device__ __forceinline__ float bf_hi(uint_t v) { return __builtin_bit_cast(float, v & 0xFFFF0000u); }

// ---------------------------------------------------------------------------
// K1: x transpose [T][D]->[D][T] (all 32 blocks) + route/aidx/nA (block 0).
// ---------------------------------------------------------------------------
__global__ void k_prep(const float* __restrict__ x, const int* __restrict__ idx,
                       const float* __restrict__ w, float* __restrict__ xT,
                       float* __restrict__ route, int* __restrict__ aidx,
                       int* __restrict__ nA) {
    const int tid = threadIdx.x;                 // 256
    const int d = blockIdx.x * 64 + (tid & 63);
    const int tq = tid >> 6;
    float4 v;
    v.x = x[(tq * 4 + 0) * DHID + d];
    v.y = x[(tq * 4 + 1) * DHID + d];
    v.z = x[(tq * 4 + 2) * DHID + d];
    v.w = x[(tq * 4 + 3) * DHID + d];
    *reinterpret_cast<float4*>(xT + d * T_TOK + tq * 4) = v;

    if (blockIdx.x != 0) return;
    __shared__ float r[NEXP * T_TOK];
    __shared__ int is64_s;
    if (tid == 0) {
        int allz = 1;
        for (int i = 1; i < 128; i += 2) allz &= (idx[i] == 0);
        is64_s = allz;
    }
    __syncthreads();
    const int is64 = is64_s;
    for (int i = tid; i < NEXP * T_TOK; i += 256) {
        const int e = i >> 4, t = i & 15;
        float s = 0.f;
#pragma unroll
        for (int k = 0; k < K_TOP; ++k) {
            const int flat = t * K_TOP + k;
            const int ev = is64 ? idx[2 * flat] : idx[flat];
            if (ev == e) s += w[flat];
        }
        r[i] = s;
        route[i] = s;
    }
    __syncthreads();
    if (tid == 0) {
        int n = 0;
        for (int e = 0; e < NEXP; ++e) {
            float s = 0.f;
            for (int t = 0; t < T_TOK; ++t) s += r[e * T_TOK + t];
            if (s != 0.f) aidx[n++] = e;
        }
        *nA = n;
    }
}

// ---- shared inner-loop machinery (both streaming kernels) ------------------
#define FMA4(t, xs)                              \
    acc0[t] = fmaf((xs), w4.x, acc0[t]);         \
    acc1[t] = fmaf((xs), w4.y, acc1[t]);         \
    acc2[t] = fmaf((xs), w4.z, acc2[t]);         \
    acc3[t] = fmaf((xs), w4.w, acc3[t]);
#define FMA_PAIR(u, t0_)                                        \
    { const float xl = bf_lo(u), xh = bf_hi(u);                 \
      FMA4(t0_, xl) FMA4((t0_) + 1, xh) }
#define STEP(jj, B)                                                         \
    { const uint4 q0 = xqw[(jj) * 2]; const uint4 q1 = xqw[(jj) * 2 + 1];   \
      const f32x4 w4 = (B);                                                 \
      FMA_PAIR(q0.x, 0) FMA_PAIR(q0.y, 2) FMA_PAIR(q0.z, 4) FMA_PAIR(q0.w, 6) \
      FMA_PAIR(q1.x, 8) FMA_PAIR(q1.y, 10) FMA_PAIR(q1.z, 12) FMA_PAIR(q1.w, 14) }
#define LDW(j) __builtin_nontemporal_load(wrow + (size_t)(j) * WSTEP)

// bf16 reduction region = 2048 uints (8 KB): layout [j(4)][tp(8)][lane(64)]
#define RW(reg)                                                         \
    { uint_t* p = lds_u + (reg) * 2048 + lane;                          \
      _Pragma("unroll") for (int tp = 0; tp < 8; ++tp) {                \
          p[(0 * 8 + tp) * 64] = pk2(acc0[2 * tp], acc0[2 * tp + 1]);   \
          p[(1 * 8 + tp) * 64] = pk2(acc1[2 * tp], acc1[2 * tp + 1]);   \
          p[(2 * 8 + tp) * 64] = pk2(acc2[2 * tp], acc2[2 * tp + 1]);   \
          p[(3 * 8 + tp) * 64] = pk2(acc3[2 * tp], acc3[2 * tp + 1]); } }
#define RR(reg)                                                         \
    { const uint_t* p = lds_u + (reg) * 2048 + lane;                    \
      _Pragma("unroll") for (int tp = 0; tp < 8; ++tp) {                \
          uint_t u;                                                     \
          u = p[(0 * 8 + tp) * 64]; acc0[2 * tp] += bf_lo(u); acc0[2 * tp + 1] += bf_hi(u); \
          u = p[(1 * 8 + tp) * 64]; acc1[2 * tp] += bf_lo(u); acc1[2 * tp + 1] += bf_hi(u); \
          u = p[(2 * 8 + tp) * 64]; acc2[2 * tp] += bf_lo(u); acc2[2 * tp + 1] += bf_hi(u); \
          u = p[(3 * 8 + tp) * 64]; acc3[2 * tp] += bf_lo(u); acc3[2 * tp + 1] += bf_hi(u); } }

// ---------------------------------------------------------------------------
// K2: fused up-proj + relu^2 + route. Block=(active e, f-quarter of 256).
// 16 waves; wave owns 128 d-rows; lane owns 4 f. x staged bf16 (64 KB), one
// barrier; depth-4 rotating weight prefetch; bf16 tree reduction 16->1.
// ---------------------------------------------------------------------------
__global__ __launch_bounds__(1024, 4) void k_up(
    const float* __restrict__ xT, const float* __restrict__ Wu,
    const float* __restrict__ route, const int* __restrict__ aidx,
    const int* __restrict__ nAp, ushort_t* __restrict__ a_buf) {
    const int b = blockIdx.x;
    if (b >= 4 * (*nAp)) return;
    const int e = aidx[b >> 2];
    const int fq = b & 3;
    const int tid = threadIdx.x;
    const int wid = tid >> 6, lane = tid & 63;

    __shared__ __align__(16) uint_t lds_u[16384];  // 64 KB

    {   // stage xT fp32 -> bf16 packed [d][tp]; linear, coalesced
        const float4* src = reinterpret_cast<const float4*>(xT);
        uint2* dst = reinterpret_cast<uint2*>(lds_u);
#pragma unroll
        for (int i = 0; i < 8; ++i) {
            const float4 v = src[tid * 8 + i];
            dst[tid * 8 + i] = make_uint2(pk2(v.x, v.y), pk2(v.z, v.w));
        }
    }
    __syncthreads();

    float acc0[16] = {}, acc1[16] = {}, acc2[16] = {}, acc3[16] = {};

    const f32x4* wrow = reinterpret_cast<const f32x4*>(
        Wu + (size_t)e * ((size_t)DHID * FINT) + (size_t)(wid * 128) * FINT
           + fq * 256 + lane * 4);
    const size_t WSTEP = FINT / 4;  // 256 f32x4 per d-row
    const uint4* xqw = reinterpret_cast<const uint4*>(lds_u) + (size_t)wid * 256;

    f32x4 b0 = LDW(0), b1 = LDW(1), b2 = LDW(2), b3 = LDW(3);
    for (int j = 0; j < 128; j += 4) {
        const bool pf = (j < 124);
        STEP(j + 0, b0) if (pf) b0 = LDW(j + 4);
        STEP(j + 1, b1) if (pf) b1 = LDW(j + 5);
        STEP(j + 2, b2) if (pf) b2 = LDW(j + 6);
        STEP(j + 3, b3) if (pf) b3 = LDW(j + 7);
    }

    // 16 -> 1 tree (x region dead, reuse whole LDS)
    __syncthreads();
    if (wid >= 8) RW(wid - 8)
    __syncthreads();
    if (wid < 8) RR(wid)
    __syncthreads();
    if (wid >= 4 && wid < 8) RW(wid - 4)
    __syncthreads();
    if (wid < 4) RR(wid)
    __syncthreads();
    if (wid >= 2 && wid < 4) RW(wid - 2)
    __syncthreads();
    if (wid < 2) RR(wid)
    __syncthreads();
    if (wid == 1) RW(0)
    __syncthreads();
    if (wid == 0) {
        RR(0)
        float rt[16];
#pragma unroll
        for (int t = 0; t < 16; ++t) rt[t] = route[e * T_TOK + t];
#define ACT(A, t) (rt[t] * fmaxf(A[t], 0.f) * fmaxf(A[t], 0.f))
        uint4* ap = reinterpret_cast<uint4*>(
            a_buf + ((size_t)e * FINT + fq * 256 + lane * 4) * T_TOK);
        uint4 o;
#define ST_COL(A, k0)                                                   \
        o.x = pk2(ACT(A, 0), ACT(A, 1));  o.y = pk2(ACT(A, 2), ACT(A, 3));   \
        o.z = pk2(ACT(A, 4), ACT(A, 5));  o.w = pk2(ACT(A, 6), ACT(A, 7));   \
        ap[k0] = o;                                                          \
        o.x = pk2(ACT(A, 8), ACT(A, 9));  o.y = pk2(ACT(A, 10), ACT(A, 11)); \
        o.z = pk2(ACT(A, 12), ACT(A, 13)); o.w = pk2(ACT(A, 14), ACT(A, 15)); \
        ap[k0 + 1] = o;
        ST_COL(acc0, 0) ST_COL(acc1, 2) ST_COL(acc2, 4) ST_COL(acc3, 6)
#undef ST_COL
#undef ACT
    }
}

// ---------------------------------------------------------------------------
// K3: down-proj. Block=(active e, d-chunk of 512). Waves (wd=wid>>3, wf=wid&7):
// lane owns 4 d at d0 = dc*512 + wd*256 + lane*4; wf owns 128 f-rows.
// a[e] staged bf16 (32 KB); depth-4 prefetch; bf16 tree 8->1 per wd-group.
// out_part is bf16 (single writer per slice).
// ---------------------------------------------------------------------------
__global__ __launch_bounds__(1024, 4) void k_down(
    const ushort_t* __restrict__ a_buf, const float* __restrict__ Wd,
    const int* __restrict__ aidx, const int* __restrict__ nAp,
    ushort_t* __restrict__ out_part) {
    const int b = blockIdx.x;
    if (b >= 4 * (*nAp)) return;
    const int e = aidx[b >> 2];
    const int dc = b & 3;
    const int tid = threadIdx.x;
    const int wid = tid >> 6, lane = tid & 63;
    const int wd = wid >> 3, wf = wid & 7;

    __shared__ __align__(16) uint_t lds_u[16384];  // 64 KB (stage uses 32 KB)

    {   // stage a[e] bf16 (32 KB) linearly
        const uint4* src = reinterpret_cast<const uint4*>(a_buf + (size_t)e * FINT * T_TOK);
        uint4* dst = reinterpret_cast<uint4*>(lds_u);
        dst[tid] = src[tid];
        dst[tid + 1024] = src[tid + 1024];
    }
    __syncthreads();

    float acc0[16] = {}, acc1[16] = {}, acc2[16] = {}, acc3[16] = {};

    const int d0 = dc * 512 + wd * 256 + lane * 4;
    const f32x4* wrow = reinterpret_cast<const f32x4*>(
        Wd + (size_t)e * ((size_t)FINT * DHID) + (size_t)(wf * 128) * DHID + d0);
    const size_t WSTEP = DHID / 4;  // 512 f32x4 per f-row
    const uint4* xqw = reinterpret_cast<const uint4*>(lds_u) + (size_t)wf * 256;

    f32x4 b0 = LDW(0), b1 = LDW(1), b2 = LDW(2), b3 = LDW(3);
    for (int j = 0; j < 128; j += 4) {
        const bool pf = (j < 124);
        STEP(j + 0, b0) if (pf) b0 = LDW(j + 4);
        STEP(j + 1, b1) if (pf) b1 = LDW(j + 5);
        STEP(j + 2, b2) if (pf) b2 = LDW(j + 6);
        STEP(j + 3, b3) if (pf) b3 = LDW(j + 7);
    }

    // 8 -> 1 per wd-group (regions wd*4 .. wd*4+3)
    __syncthreads();
    if (wf >= 4) RW(wd * 4 + wf - 4)
    __syncthreads();
    if (wf < 4) RR(wd * 4 + wf)
    __syncthreads();
    if (wf == 2 || wf == 3) RW(wd * 4 + wf - 2)
    __syncthreads();
    if (wf < 2) RR(wd * 4 + wf)
    __syncthreads();
    if (wf == 1) RW(wd * 4)
    __syncthreads();
    if (wf == 0) {
        RR(wd * 4)
        ushort_t* op = out_part + (size_t)e * (T_TOK * DHID) + d0;
#pragma unroll
        for (int t = 0; t < 16; ++t) {
            uint2 u;
            u.x = pk2(acc0[t], acc1[t]);
            u.y = pk2(acc2[t], acc3[t]);
            *reinterpret_cast<uint2*>(op + (size_t)t * DHID) = u;
        }
    }
}

// ---------------------------------------------------------------------------
// K4a: partial[g][t][d] = sum over active experts a = g, g+8, ... (fp32).
// grid (32, 8) x 256 -> 256 blocks; fully overwrites partial.
// ---------------------------------------------------------------------------
__global__ void k_comb1(const ushort_t* __restrict__ out_part, const int* __restrict__ aidx,
                        const int* __restrict__ nAp, float* __restrict__ partial) {
    const int g = blockIdx.y;
    const int i = blockIdx.x * 256 + threadIdx.x;  // [0, T*D/4)
    const int nA = *nAp;
    const int t = i >> 9;
    const int d = (i & 511) * 4;
    const size_t off = (size_t)t * DHID + d;
    float s0 = 0.f, s1 = 0.f, s2 = 0.f, s3 = 0.f;
    for (int a = g; a < nA; a += 8) {
        const uint2 v = *reinterpret_cast<const uint2*>(
            out_part + (size_t)aidx[a] * (T_TOK * DHID) + off);
        s0 += bf_lo(v.x); s1 += bf_hi(v.x);
        s2 += bf_lo(v.y); s3 += bf_hi(v.y);
    }
    *reinterpret_cast<float4*>(partial + (size_t)g * (T_TOK * DHID) + off) =
        make_float4(s0, s1, s2, s3);
}

// ---------------------------------------------------------------------------
// K4b: out[t][d] = sum_g partial[g][t][d]. Fully overwrites d_out.
// ---------------------------------------------------------------------------
__global__ void k_comb2(const float* __restrict__ partial, float* __restrict__ out) {
    const int i = blockIdx.x * 256 + threadIdx.x;  // [0, T*D/4)
    const size_t off = (size_t)i * 4;
    float4 s = make_float4(0.f, 0.f, 0.f, 0.f);
#pragma unroll
    for (int g = 0; g < 8; ++g) {
        const float4 v = *reinterpret_cast<const float4*>(
            partial + (size_t)g * (T_TOK * DHID) + off);
        s.x += v.x; s.y += v.y; s.z += v.z; s.w += v.w;
    }
    *reinterpret_cast<float4*>(out + off) = s;
}

// ---------------------------------------------------------------------------
extern "C" void kernel_launch(void* const* d_in, const int* in_sizes, int n_in,
                              void* d_out, int out_size, void* d_ws, size_t ws_size,
                              hipStream_t stream) {
    (void)in_sizes; (void)n_in; (void)out_size; (void)ws_size;
    const float* x   = (const float*)d_in[0];
    const int*   idx = (const int*)d_in[1];
    const float* w   = (const float*)d_in[2];
    const float* Wu  = (const float*)d_in[3];
    const float* Wd  = (const float*)d_in[4];
    float* out = (float*)d_out;

    char* ws = (char*)d_ws;
    float*    route    = (float*)(ws + ROUTE_OFF);
    int*      aidx     = (int*)(ws + AIDX_OFF);
    int*      nA       = (int*)(ws + NA_OFF);
    float*    xT       = (float*)(ws + XT_OFF);
    ushort_t* a_buf    = (ushort_t*)(ws + ABUF_OFF);
    ushort_t* out_part = (ushort_t*)(ws + OPART_OFF);
    float*    partial  = (float*)(ws + PART8_OFF);

    k_prep<<<DHID / 64, 256, 0, stream>>>(x, idx, w, xT, route, aidx, nA);
    k_up<<<4 * NEXP, 1024, 0, stream>>>(xT, Wu, route, aidx, nA, a_buf);
    k_down<<<4 * NEXP, 1024, 0, stream>>>(a_buf, Wd, aidx, nA, out_part);
    k_comb1<<<dim3(32, 8), 256, 0, stream>>>(out_part, aidx, nA, partial);
    k_comb2<<<32, 256, 0, stream>>>(partial, out);
}